// Round 5
// baseline (992.710 us; speedup 1.0000x reference)
//
#include <hip/hip_runtime.h>

// DCN module on MI355X — fissioned design:
//   A) assign_kernel: bf16-split MFMA argmin -> labels + loss (no seg-sum,
//      65 KB LDS -> 2 blocks/CU, 32 waves/CU)
//   B) segsum_kernel: streaming re-read of emb + labels -> LDS ds_add seg-sum
//   C) finalize_kernel: centers/counts/loss epilogue
//
// Output (float32 flat): [0,N) labels | [N] loss | centers [K][D] | counts [K]

typedef __attribute__((ext_vector_type(8))) short bf16x8;
typedef __attribute__((ext_vector_type(4))) float f32x4;

constexpr int K = 256;
constexpr int D = 64;

constexpr int BLK_A = 1024;     // 16 waves
constexpr int GRID_A = 512;     // 2 blocks/CU
constexpr int WPB_A = BLK_A / 64;

constexpr int BLK_B = 1024;
constexpr int GRID_B = 256;     // 1 block/CU, 16 waves

struct alignas(16) PackW { unsigned int w[4]; };

// fire-and-forget LDS f32 atomic add (low 32 bits of generic ptr = LDS offset)
#define DS_ADD_F32(addr32, val) \
  asm volatile("ds_add_f32 %0, %1" :: "v"(addr32), "v"(val))

__device__ __forceinline__ unsigned int pack_hi(unsigned int a, unsigned int b) {
  return (a >> 16) | (b & 0xffff0000u);
}

__device__ __forceinline__ void split8(const float4 a, const float4 b,
                                       bf16x8& s0, bf16x8& s1) {
  PackW p0, p1;
  const float fa[8] = {a.x, a.y, a.z, a.w, b.x, b.y, b.z, b.w};
#pragma unroll
  for (int i = 0; i < 4; ++i) {
    float f0 = fa[2 * i], f1 = fa[2 * i + 1];
    unsigned u0 = __float_as_uint(f0), u1 = __float_as_uint(f1);
    p0.w[i] = pack_hi(u0, u1);
    float r0 = f0 - __uint_as_float(u0 & 0xffff0000u);
    float r1 = f1 - __uint_as_float(u1 & 0xffff0000u);
    p1.w[i] = pack_hi(__float_as_uint(r0), __float_as_uint(r1));
  }
  s0 = __builtin_bit_cast(bf16x8, p0);
  s1 = __builtin_bit_cast(bf16x8, p1);
}

// ---------------- A: assign (labels + loss only) ----------------
__global__ __launch_bounds__(BLK_A, 8) void assign_kernel(
    const float* __restrict__ emb,
    const float* __restrict__ centers,
    float* __restrict__ out_labels,
    float* __restrict__ ws_loss,
    int N)
{
  __shared__ __align__(16) unsigned short Bls[2 * K * D];   // 64 KB
  __shared__ float hneg_lds[K];
  __shared__ float red[WPB_A];

  const int tid = threadIdx.x;

  for (int e = tid; e < K * D; e += BLK_A) {
    int j = e >> 6, d = e & 63;
    float cv = centers[e];
    unsigned u = __float_as_uint(cv);
    unsigned short h0 = (unsigned short)(u >> 16);
    float r = cv - __uint_as_float(u & 0xffff0000u);
    unsigned short h1 = (unsigned short)(__float_as_uint(r) >> 16);
    int nt = j >> 4, c = j & 15;
    int si = nt * 1024 + c * 64 + (d ^ ((c & 7) << 3));
    Bls[si] = h0;
    Bls[16384 + si] = h1;
  }
  if (tid < K) {
    const float4* cp = (const float4*)(centers + tid * D);
    float s = 0.f;
#pragma unroll
    for (int q = 0; q < 16; ++q) {
      float4 v = cp[q];
      s = fmaf(v.x, v.x, s); s = fmaf(v.y, v.y, s);
      s = fmaf(v.z, v.z, s); s = fmaf(v.w, v.w, s);
    }
    hneg_lds[tid] = -0.5f * s;
  }
  __syncthreads();

  const int lane = tid & 63;
  const int wid  = tid >> 6;
  const int g    = lane >> 4;
  const int cc   = lane & 15;
  const int swzm = (cc & 7) << 3;
  const int bRow = cc * 64;
  const int bk0 = (8 * g) ^ swzm;
  const int bk1 = (32 + 8 * g) ^ swzm;

  float hreg[16];
#pragma unroll
  for (int nt = 0; nt < 16; ++nt) hreg[nt] = hneg_lds[nt * 16 + cc];

  float lossS = 0.f, lossX = 0.f;
  const int TILES = N >> 5;

  for (int tile = blockIdx.x * WPB_A + wid; tile < TILES; tile += GRID_A * WPB_A) {
    const int base = tile << 5;

    float4 xa[2][2][2];
    bf16x8 fx[2][2][2];
#pragma unroll
    for (int Mt = 0; Mt < 2; ++Mt) {
#pragma unroll
      for (int ks = 0; ks < 2; ++ks) {
        const float4* rp = (const float4*)(emb + (size_t)(base + Mt * 16 + cc) * D + ks * 32 + g * 8);
        xa[Mt][ks][0] = rp[0];
        xa[Mt][ks][1] = rp[1];
      }
#pragma unroll
      for (int ks = 0; ks < 2; ++ks)
        split8(xa[Mt][ks][0], xa[Mt][ks][1], fx[Mt][ks][0], fx[Mt][ks][1]);
#pragma unroll
      for (int ks = 0; ks < 2; ++ks)
#pragma unroll
        for (int h = 0; h < 2; ++h) {
          float4 v = xa[Mt][ks][h];
          lossX = fmaf(v.x, v.x, lossX); lossX = fmaf(v.y, v.y, lossX);
          lossX = fmaf(v.z, v.z, lossX); lossX = fmaf(v.w, v.w, lossX);
        }
    }

    float bE[2][4];
#pragma unroll
    for (int Mt = 0; Mt < 2; ++Mt)
#pragma unroll
      for (int r = 0; r < 4; ++r) bE[Mt][r] = -3.0e38f;

#pragma unroll
    for (int nt = 0; nt < 16; ++nt) {
      float h = hreg[nt];
      f32x4 ci = {h, h, h, h};
      bf16x8 b00 = *(const bf16x8*)&Bls[nt * 1024 + bRow + bk0];
      bf16x8 b01 = *(const bf16x8*)&Bls[16384 + nt * 1024 + bRow + bk0];
      bf16x8 b10 = *(const bf16x8*)&Bls[nt * 1024 + bRow + bk1];
      bf16x8 b11 = *(const bf16x8*)&Bls[16384 + nt * 1024 + bRow + bk1];
      f32x4 a0, a1;
      a0 = __builtin_amdgcn_mfma_f32_16x16x32_bf16(fx[0][0][0], b00, ci, 0, 0, 0);
      a0 = __builtin_amdgcn_mfma_f32_16x16x32_bf16(fx[0][0][1], b00, a0, 0, 0, 0);
      a0 = __builtin_amdgcn_mfma_f32_16x16x32_bf16(fx[0][0][0], b01, a0, 0, 0, 0);
      a0 = __builtin_amdgcn_mfma_f32_16x16x32_bf16(fx[0][1][0], b10, a0, 0, 0, 0);
      a0 = __builtin_amdgcn_mfma_f32_16x16x32_bf16(fx[0][1][1], b10, a0, 0, 0, 0);
      a0 = __builtin_amdgcn_mfma_f32_16x16x32_bf16(fx[0][1][0], b11, a0, 0, 0, 0);
      a1 = __builtin_amdgcn_mfma_f32_16x16x32_bf16(fx[1][0][0], b00, ci, 0, 0, 0);
      a1 = __builtin_amdgcn_mfma_f32_16x16x32_bf16(fx[1][0][1], b00, a1, 0, 0, 0);
      a1 = __builtin_amdgcn_mfma_f32_16x16x32_bf16(fx[1][0][0], b01, a1, 0, 0, 0);
      a1 = __builtin_amdgcn_mfma_f32_16x16x32_bf16(fx[1][1][0], b10, a1, 0, 0, 0);
      a1 = __builtin_amdgcn_mfma_f32_16x16x32_bf16(fx[1][1][1], b10, a1, 0, 0, 0);
      a1 = __builtin_amdgcn_mfma_f32_16x16x32_bf16(fx[1][1][0], b11, a1, 0, 0, 0);

      unsigned ib = (unsigned)(nt << 4) | (unsigned)cc;
#pragma unroll
      for (int r = 0; r < 4; ++r) {
        bE[0][r] = fmaxf(bE[0][r], __uint_as_float((__float_as_uint(a0[r]) & 0xFFFFFF00u) | ib));
        bE[1][r] = fmaxf(bE[1][r], __uint_as_float((__float_as_uint(a1[r]) & 0xFFFFFF00u) | ib));
      }
    }

#pragma unroll
    for (int Mt = 0; Mt < 2; ++Mt)
#pragma unroll
      for (int r = 0; r < 4; ++r)
#pragma unroll
        for (int m = 1; m <= 8; m <<= 1)
          bE[Mt][r] = fmaxf(bE[Mt][r], __shfl_xor(bE[Mt][r], m));

#pragma unroll
    for (int Mt = 0; Mt < 2; ++Mt) {
      float v01 = (cc & 1) ? bE[Mt][1] : bE[Mt][0];
      float v23 = (cc & 1) ? bE[Mt][3] : bE[Mt][2];
      float vv  = (cc & 2) ? v23 : v01;
      if (cc < 4) {
        int vi = (int)(__float_as_uint(vv) & 255u);
        out_labels[base + Mt * 16 + g * 4 + cc] = (float)vi;
        lossS += vv;
      }
    }
  }

  float acc = fmaf(-2.f, lossS, lossX);
#pragma unroll
  for (int off = 32; off > 0; off >>= 1) acc += __shfl_down(acc, off);
  if (lane == 0) red[wid] = acc;
  __syncthreads();
  if (tid == 0) {
    float t = 0.f;
#pragma unroll
    for (int w = 0; w < WPB_A; ++w) t += red[w];
    unsafeAtomicAdd(ws_loss, t);
  }
}

// ---------------- B: streaming segment sum ----------------
__global__ __launch_bounds__(BLK_B, 8) void segsum_kernel(
    const float* __restrict__ emb,
    const float* __restrict__ labels_f,
    float* __restrict__ ws_seg,
    int*   __restrict__ ws_cnt,
    int N)
{
  __shared__ float seg_lds[K * D];   // [k][d^(k&31)]  64 KB
  __shared__ int   cnt_lds[K];

  const int tid = threadIdx.x;
  for (int e = tid; e < K * D; e += BLK_B) seg_lds[e] = 0.f;
  if (tid < K) cnt_lds[tid] = 0;
  __syncthreads();

  const unsigned segbase = (unsigned)(size_t)seg_lds;
  const int q = tid & 3;                    // 4 lanes per sample
  const int SPP = GRID_B * BLK_B / 4;       // samples per pass (65536)

  for (int s = (blockIdx.x * BLK_B + tid) >> 2; s < N; s += SPP) {
    int lbl = (int)labels_f[s];
    const float4* rp = (const float4*)(emb + (size_t)s * D + q * 16);
    float4 v0 = rp[0], v1 = rp[1], v2 = rp[2], v3 = rp[3];
    unsigned sb = segbase + ((unsigned)lbl << 8);
    int sw = lbl & 31;
    int d0 = q * 16;
    DS_ADD_F32(sb + (unsigned)(((d0 +  0) ^ sw) << 2), v0.x);
    DS_ADD_F32(sb + (unsigned)(((d0 +  1) ^ sw) << 2), v0.y);
    DS_ADD_F32(sb + (unsigned)(((d0 +  2) ^ sw) << 2), v0.z);
    DS_ADD_F32(sb + (unsigned)(((d0 +  3) ^ sw) << 2), v0.w);
    DS_ADD_F32(sb + (unsigned)(((d0 +  4) ^ sw) << 2), v1.x);
    DS_ADD_F32(sb + (unsigned)(((d0 +  5) ^ sw) << 2), v1.y);
    DS_ADD_F32(sb + (unsigned)(((d0 +  6) ^ sw) << 2), v1.z);
    DS_ADD_F32(sb + (unsigned)(((d0 +  7) ^ sw) << 2), v1.w);
    DS_ADD_F32(sb + (unsigned)(((d0 +  8) ^ sw) << 2), v2.x);
    DS_ADD_F32(sb + (unsigned)(((d0 +  9) ^ sw) << 2), v2.y);
    DS_ADD_F32(sb + (unsigned)(((d0 + 10) ^ sw) << 2), v2.z);
    DS_ADD_F32(sb + (unsigned)(((d0 + 11) ^ sw) << 2), v2.w);
    DS_ADD_F32(sb + (unsigned)(((d0 + 12) ^ sw) << 2), v3.x);
    DS_ADD_F32(sb + (unsigned)(((d0 + 13) ^ sw) << 2), v3.y);
    DS_ADD_F32(sb + (unsigned)(((d0 + 14) ^ sw) << 2), v3.z);
    DS_ADD_F32(sb + (unsigned)(((d0 + 15) ^ sw) << 2), v3.w);
    if (q == 0) atomicAdd(&cnt_lds[lbl], 1);
  }

  asm volatile("s_waitcnt lgkmcnt(0)" ::: "memory");
  __syncthreads();

  for (int e = tid; e < K * D; e += BLK_B) {
    int k = e >> 6, d = e & 63;
    unsafeAtomicAdd(&ws_seg[e], seg_lds[(k << 6) + (d ^ (k & 31))]);
  }
  if (tid < K) atomicAdd(&ws_cnt[tid], cnt_lds[tid]);
}

// ---------------- C: finalize ----------------
__global__ void finalize_kernel(
    const float* __restrict__ centers,
    const int* __restrict__ counts,
    const float* __restrict__ ws_seg,
    const int* __restrict__ ws_cnt,
    const float* __restrict__ ws_loss,
    float* __restrict__ out_loss,
    float* __restrict__ out_centers,
    float* __restrict__ out_counts,
    int N)
{
  int idx = blockIdx.x * blockDim.x + threadIdx.x;
  if (idx < K * D) {
    int k = idx >> 6;
    float oldw = (float)counts[k];
    float neww = (float)(counts[k] + ws_cnt[k]);
    out_centers[idx] = fmaf(oldw, centers[idx], ws_seg[idx]) / neww;
  }
  if (idx < K) out_counts[idx] = (float)(counts[idx] + ws_cnt[idx]);
  if (idx == 0) out_loss[0] = ws_loss[0] / (float)N;
}

extern "C" void kernel_launch(void* const* d_in, const int* in_sizes, int n_in,
                              void* d_out, int out_size, void* d_ws, size_t ws_size,
                              hipStream_t stream) {
  const float* emb     = (const float*)d_in[0];
  const float* centers = (const float*)d_in[1];
  const int*   counts  = (const int*)d_in[2];

  const int Kn = in_sizes[2];        // 256
  const int Dn = in_sizes[1] / Kn;   // 64
  const int N  = in_sizes[0] / Dn;   // 500000

  float* out         = (float*)d_out;
  float* out_labels  = out;
  float* out_loss    = out + N;
  float* out_centers = out + N + 1;
  float* out_counts  = out + N + 1 + (size_t)Kn * Dn;

  float* ws_seg  = (float*)d_ws;
  int*   ws_cnt  = (int*)(ws_seg + (size_t)Kn * Dn);
  float* ws_loss = (float*)(ws_cnt + Kn);

  hipMemsetAsync(d_ws, 0, (size_t)(Kn * Dn + Kn + 1) * sizeof(float), stream);

  hipLaunchKernelGGL(assign_kernel, dim3(GRID_A), dim3(BLK_A), 0, stream,
                     emb, centers, out_labels, ws_loss, N);

  hipLaunchKernelGGL(segsum_kernel, dim3(GRID_B), dim3(BLK_B), 0, stream,
                     emb, out_labels, ws_seg, ws_cnt, N);

  hipLaunchKernelGGL(finalize_kernel, dim3((Kn * Dn + 255) / 256), dim3(256), 0, stream,
                     centers, counts, ws_seg, ws_cnt, ws_loss,
                     out_loss, out_centers, out_counts, N);
}

// Round 6
// 751.220 us; speedup vs baseline: 1.3215x; 1.3215x over previous
//
#include <hip/hip_runtime.h>

// DCN module on MI355X — fissioned design:
//   A) assign_kernel: bf16-split MFMA argmin -> labels + loss
//      (65 KB LDS, 512-thr blocks, LB(512,4) -> ~84 VGPR, NO SPILLS;
//       2 blocks/CU = 16 waves/CU)
//   B) segsum_kernel: streaming re-read of emb + labels -> LDS ds_add seg-sum
//   C) finalize_kernel: centers/counts/loss epilogue
//
// Round 5 lesson (measured): LB(1024,8) capped VGPRs at 64 -> massive scratch
// spills -> 2.28 GB HBM traffic -> 686 us. Never request more occupancy than
// the register budget affords.
//
// Output (float32 flat): [0,N) labels | [N] loss | centers [K][D] | counts [K]

typedef __attribute__((ext_vector_type(8))) short bf16x8;
typedef __attribute__((ext_vector_type(4))) float f32x4;

constexpr int K = 256;
constexpr int D = 64;

constexpr int BLK_A = 512;      // 8 waves
constexpr int GRID_A = 1024;    // 2 blocks/CU (LDS 2x65KB = 130KB <= 160KB)
constexpr int WPB_A = BLK_A / 64;

constexpr int BLK_B = 1024;
constexpr int GRID_B = 512;     // 2 blocks/CU

struct alignas(16) PackW { unsigned int w[4]; };

// fire-and-forget LDS f32 atomic add (low 32 bits of generic ptr = LDS offset)
#define DS_ADD_F32(addr32, val) \
  asm volatile("ds_add_f32 %0, %1" :: "v"(addr32), "v"(val))

__device__ __forceinline__ unsigned int pack_hi(unsigned int a, unsigned int b) {
  return (a >> 16) | (b & 0xffff0000u);
}

__device__ __forceinline__ void split8(const float4 a, const float4 b,
                                       bf16x8& s0, bf16x8& s1) {
  PackW p0, p1;
  const float fa[8] = {a.x, a.y, a.z, a.w, b.x, b.y, b.z, b.w};
#pragma unroll
  for (int i = 0; i < 4; ++i) {
    float f0 = fa[2 * i], f1 = fa[2 * i + 1];
    unsigned u0 = __float_as_uint(f0), u1 = __float_as_uint(f1);
    p0.w[i] = pack_hi(u0, u1);
    float r0 = f0 - __uint_as_float(u0 & 0xffff0000u);
    float r1 = f1 - __uint_as_float(u1 & 0xffff0000u);
    p1.w[i] = pack_hi(__float_as_uint(r0), __float_as_uint(r1));
  }
  s0 = __builtin_bit_cast(bf16x8, p0);
  s1 = __builtin_bit_cast(bf16x8, p1);
}

// ---------------- A: assign (labels + loss only) ----------------
__global__ __launch_bounds__(BLK_A, 4) void assign_kernel(
    const float* __restrict__ emb,
    const float* __restrict__ centers,
    float* __restrict__ out_labels,
    float* __restrict__ ws_loss,
    int N)
{
  __shared__ __align__(16) unsigned short Bls[2 * K * D];   // 64 KB
  __shared__ float hneg_lds[K];
  __shared__ float red[WPB_A];

  const int tid = threadIdx.x;

  for (int e = tid; e < K * D; e += BLK_A) {
    int j = e >> 6, d = e & 63;
    float cv = centers[e];
    unsigned u = __float_as_uint(cv);
    unsigned short h0 = (unsigned short)(u >> 16);
    float r = cv - __uint_as_float(u & 0xffff0000u);
    unsigned short h1 = (unsigned short)(__float_as_uint(r) >> 16);
    int nt = j >> 4, c = j & 15;
    int si = nt * 1024 + c * 64 + (d ^ ((c & 7) << 3));
    Bls[si] = h0;
    Bls[16384 + si] = h1;
  }
  if (tid < K) {
    const float4* cp = (const float4*)(centers + tid * D);
    float s = 0.f;
#pragma unroll
    for (int q = 0; q < 16; ++q) {
      float4 v = cp[q];
      s = fmaf(v.x, v.x, s); s = fmaf(v.y, v.y, s);
      s = fmaf(v.z, v.z, s); s = fmaf(v.w, v.w, s);
    }
    hneg_lds[tid] = -0.5f * s;
  }
  __syncthreads();

  const int lane = tid & 63;
  const int wid  = tid >> 6;
  const int g    = lane >> 4;
  const int cc   = lane & 15;
  const int swzm = (cc & 7) << 3;
  const int bRow = cc * 64;
  const int bk0 = (8 * g) ^ swzm;
  const int bk1 = (32 + 8 * g) ^ swzm;

  float hreg[16];
#pragma unroll
  for (int nt = 0; nt < 16; ++nt) hreg[nt] = hneg_lds[nt * 16 + cc];

  float lossS = 0.f, lossX = 0.f;
  const int TILES = N >> 5;

  for (int tile = blockIdx.x * WPB_A + wid; tile < TILES; tile += GRID_A * WPB_A) {
    const int base = tile << 5;

    float4 xa[2][2][2];
    bf16x8 fx[2][2][2];
#pragma unroll
    for (int Mt = 0; Mt < 2; ++Mt) {
#pragma unroll
      for (int ks = 0; ks < 2; ++ks) {
        const float4* rp = (const float4*)(emb + (size_t)(base + Mt * 16 + cc) * D + ks * 32 + g * 8);
        xa[Mt][ks][0] = rp[0];
        xa[Mt][ks][1] = rp[1];
      }
#pragma unroll
      for (int ks = 0; ks < 2; ++ks)
        split8(xa[Mt][ks][0], xa[Mt][ks][1], fx[Mt][ks][0], fx[Mt][ks][1]);
#pragma unroll
      for (int ks = 0; ks < 2; ++ks)
#pragma unroll
        for (int h = 0; h < 2; ++h) {
          float4 v = xa[Mt][ks][h];
          lossX = fmaf(v.x, v.x, lossX); lossX = fmaf(v.y, v.y, lossX);
          lossX = fmaf(v.z, v.z, lossX); lossX = fmaf(v.w, v.w, lossX);
        }
    }

    float bE[2][4];
#pragma unroll
    for (int Mt = 0; Mt < 2; ++Mt)
#pragma unroll
      for (int r = 0; r < 4; ++r) bE[Mt][r] = -3.0e38f;

#pragma unroll
    for (int nt = 0; nt < 16; ++nt) {
      float h = hreg[nt];
      f32x4 ci = {h, h, h, h};
      bf16x8 b00 = *(const bf16x8*)&Bls[nt * 1024 + bRow + bk0];
      bf16x8 b01 = *(const bf16x8*)&Bls[16384 + nt * 1024 + bRow + bk0];
      bf16x8 b10 = *(const bf16x8*)&Bls[nt * 1024 + bRow + bk1];
      bf16x8 b11 = *(const bf16x8*)&Bls[16384 + nt * 1024 + bRow + bk1];
      f32x4 a0, a1;
      a0 = __builtin_amdgcn_mfma_f32_16x16x32_bf16(fx[0][0][0], b00, ci, 0, 0, 0);
      a0 = __builtin_amdgcn_mfma_f32_16x16x32_bf16(fx[0][0][1], b00, a0, 0, 0, 0);
      a0 = __builtin_amdgcn_mfma_f32_16x16x32_bf16(fx[0][0][0], b01, a0, 0, 0, 0);
      a0 = __builtin_amdgcn_mfma_f32_16x16x32_bf16(fx[0][1][0], b10, a0, 0, 0, 0);
      a0 = __builtin_amdgcn_mfma_f32_16x16x32_bf16(fx[0][1][1], b10, a0, 0, 0, 0);
      a0 = __builtin_amdgcn_mfma_f32_16x16x32_bf16(fx[0][1][0], b11, a0, 0, 0, 0);
      a1 = __builtin_amdgcn_mfma_f32_16x16x32_bf16(fx[1][0][0], b00, ci, 0, 0, 0);
      a1 = __builtin_amdgcn_mfma_f32_16x16x32_bf16(fx[1][0][1], b00, a1, 0, 0, 0);
      a1 = __builtin_amdgcn_mfma_f32_16x16x32_bf16(fx[1][0][0], b01, a1, 0, 0, 0);
      a1 = __builtin_amdgcn_mfma_f32_16x16x32_bf16(fx[1][1][0], b10, a1, 0, 0, 0);
      a1 = __builtin_amdgcn_mfma_f32_16x16x32_bf16(fx[1][1][1], b10, a1, 0, 0, 0);
      a1 = __builtin_amdgcn_mfma_f32_16x16x32_bf16(fx[1][1][0], b11, a1, 0, 0, 0);

      unsigned ib = (unsigned)(nt << 4) | (unsigned)cc;
#pragma unroll
      for (int r = 0; r < 4; ++r) {
        bE[0][r] = fmaxf(bE[0][r], __uint_as_float((__float_as_uint(a0[r]) & 0xFFFFFF00u) | ib));
        bE[1][r] = fmaxf(bE[1][r], __uint_as_float((__float_as_uint(a1[r]) & 0xFFFFFF00u) | ib));
      }
    }

#pragma unroll
    for (int Mt = 0; Mt < 2; ++Mt)
#pragma unroll
      for (int r = 0; r < 4; ++r)
#pragma unroll
        for (int m = 1; m <= 8; m <<= 1)
          bE[Mt][r] = fmaxf(bE[Mt][r], __shfl_xor(bE[Mt][r], m));

#pragma unroll
    for (int Mt = 0; Mt < 2; ++Mt) {
      float v01 = (cc & 1) ? bE[Mt][1] : bE[Mt][0];
      float v23 = (cc & 1) ? bE[Mt][3] : bE[Mt][2];
      float vv  = (cc & 2) ? v23 : v01;
      if (cc < 4) {
        int vi = (int)(__float_as_uint(vv) & 255u);
        out_labels[base + Mt * 16 + g * 4 + cc] = (float)vi;
        lossS += vv;
      }
    }
  }

  float acc = fmaf(-2.f, lossS, lossX);
#pragma unroll
  for (int off = 32; off > 0; off >>= 1) acc += __shfl_down(acc, off);
  if (lane == 0) red[wid] = acc;
  __syncthreads();
  if (tid == 0) {
    float t = 0.f;
#pragma unroll
    for (int w = 0; w < WPB_A; ++w) t += red[w];
    unsafeAtomicAdd(ws_loss, t);
  }
}

// ---------------- B: streaming segment sum ----------------
__global__ __launch_bounds__(BLK_B, 4) void segsum_kernel(
    const float* __restrict__ emb,
    const float* __restrict__ labels_f,
    float* __restrict__ ws_seg,
    int*   __restrict__ ws_cnt,
    int N)
{
  __shared__ float seg_lds[K * D];   // [k][d^(k&31)]  64 KB
  __shared__ int   cnt_lds[K];

  const int tid = threadIdx.x;
  for (int e = tid; e < K * D; e += BLK_B) seg_lds[e] = 0.f;
  if (tid < K) cnt_lds[tid] = 0;
  __syncthreads();

  const unsigned segbase = (unsigned)(size_t)seg_lds;
  const int q = tid & 3;                    // 4 lanes per sample
  const int SPP = GRID_B * BLK_B / 4;       // samples per pass (131072)

  for (int s = (blockIdx.x * BLK_B + tid) >> 2; s < N; s += SPP) {
    int lbl = (int)labels_f[s];
    const float4* rp = (const float4*)(emb + (size_t)s * D + q * 16);
    float4 v0 = rp[0], v1 = rp[1], v2 = rp[2], v3 = rp[3];
    unsigned sb = segbase + ((unsigned)lbl << 8);
    int sw = lbl & 31;
    int d0 = q * 16;
    DS_ADD_F32(sb + (unsigned)(((d0 +  0) ^ sw) << 2), v0.x);
    DS_ADD_F32(sb + (unsigned)(((d0 +  1) ^ sw) << 2), v0.y);
    DS_ADD_F32(sb + (unsigned)(((d0 +  2) ^ sw) << 2), v0.z);
    DS_ADD_F32(sb + (unsigned)(((d0 +  3) ^ sw) << 2), v0.w);
    DS_ADD_F32(sb + (unsigned)(((d0 +  4) ^ sw) << 2), v1.x);
    DS_ADD_F32(sb + (unsigned)(((d0 +  5) ^ sw) << 2), v1.y);
    DS_ADD_F32(sb + (unsigned)(((d0 +  6) ^ sw) << 2), v1.z);
    DS_ADD_F32(sb + (unsigned)(((d0 +  7) ^ sw) << 2), v1.w);
    DS_ADD_F32(sb + (unsigned)(((d0 +  8) ^ sw) << 2), v2.x);
    DS_ADD_F32(sb + (unsigned)(((d0 +  9) ^ sw) << 2), v2.y);
    DS_ADD_F32(sb + (unsigned)(((d0 + 10) ^ sw) << 2), v2.z);
    DS_ADD_F32(sb + (unsigned)(((d0 + 11) ^ sw) << 2), v2.w);
    DS_ADD_F32(sb + (unsigned)(((d0 + 12) ^ sw) << 2), v3.x);
    DS_ADD_F32(sb + (unsigned)(((d0 + 13) ^ sw) << 2), v3.y);
    DS_ADD_F32(sb + (unsigned)(((d0 + 14) ^ sw) << 2), v3.z);
    DS_ADD_F32(sb + (unsigned)(((d0 + 15) ^ sw) << 2), v3.w);
    if (q == 0) atomicAdd(&cnt_lds[lbl], 1);
  }

  asm volatile("s_waitcnt lgkmcnt(0)" ::: "memory");
  __syncthreads();

  for (int e = tid; e < K * D; e += BLK_B) {
    int k = e >> 6, d = e & 63;
    unsafeAtomicAdd(&ws_seg[e], seg_lds[(k << 6) + (d ^ (k & 31))]);
  }
  if (tid < K) atomicAdd(&ws_cnt[tid], cnt_lds[tid]);
}

// ---------------- C: finalize ----------------
__global__ void finalize_kernel(
    const float* __restrict__ centers,
    const int* __restrict__ counts,
    const float* __restrict__ ws_seg,
    const int* __restrict__ ws_cnt,
    const float* __restrict__ ws_loss,
    float* __restrict__ out_loss,
    float* __restrict__ out_centers,
    float* __restrict__ out_counts,
    int N)
{
  int idx = blockIdx.x * blockDim.x + threadIdx.x;
  if (idx < K * D) {
    int k = idx >> 6;
    float oldw = (float)counts[k];
    float neww = (float)(counts[k] + ws_cnt[k]);
    out_centers[idx] = fmaf(oldw, centers[idx], ws_seg[idx]) / neww;
  }
  if (idx < K) out_counts[idx] = (float)(counts[idx] + ws_cnt[idx]);
  if (idx == 0) out_loss[0] = ws_loss[0] / (float)N;
}

extern "C" void kernel_launch(void* const* d_in, const int* in_sizes, int n_in,
                              void* d_out, int out_size, void* d_ws, size_t ws_size,
                              hipStream_t stream) {
  const float* emb     = (const float*)d_in[0];
  const float* centers = (const float*)d_in[1];
  const int*   counts  = (const int*)d_in[2];

  const int Kn = in_sizes[2];        // 256
  const int Dn = in_sizes[1] / Kn;   // 64
  const int N  = in_sizes[0] / Dn;   // 500000

  float* out         = (float*)d_out;
  float* out_labels  = out;
  float* out_loss    = out + N;
  float* out_centers = out + N + 1;
  float* out_counts  = out + N + 1 + (size_t)Kn * Dn;

  float* ws_seg  = (float*)d_ws;
  int*   ws_cnt  = (int*)(ws_seg + (size_t)Kn * Dn);
  float* ws_loss = (float*)(ws_cnt + Kn);

  hipMemsetAsync(d_ws, 0, (size_t)(Kn * Dn + Kn + 1) * sizeof(float), stream);

  hipLaunchKernelGGL(assign_kernel, dim3(GRID_A), dim3(BLK_A), 0, stream,
                     emb, centers, out_labels, ws_loss, N);

  hipLaunchKernelGGL(segsum_kernel, dim3(GRID_B), dim3(BLK_B), 0, stream,
                     emb, out_labels, ws_seg, ws_cnt, N);

  hipLaunchKernelGGL(finalize_kernel, dim3((Kn * Dn + 255) / 256), dim3(256), 0, stream,
                     centers, counts, ws_seg, ws_cnt, ws_loss,
                     out_loss, out_centers, out_counts, N);
}

// Round 7
// 602.287 us; speedup vs baseline: 1.6482x; 1.2473x over previous
//
#include <hip/hip_runtime.h>

// DCN module on MI355X — fissioned design:
//   A) assign_kernel: bf16-split MFMA argmin -> labels + loss
//   B) segsum_kernel: streaming re-read of emb + labels -> LDS ds_add seg-sum
//   C) finalize_kernel: centers/counts/loss epilogue
//
// Round 5/6 lesson (measured): __launch_bounds__ 2nd arg of 8 -> 32-VGPR-class
// allocation (2.28 GB spill traffic); 4 -> 64 VGPR (1.46 GB spill). Round 2's
// value of 3 gave 84 VGPR, zero spill. Keep the cap loose (=2): LDS already
// limits occupancy to 2 blocks/CU; extra "requested occupancy" only strangles
// the register allocator.
//
// Output (float32 flat): [0,N) labels | [N] loss | centers [K][D] | counts [K]

typedef __attribute__((ext_vector_type(8))) short bf16x8;
typedef __attribute__((ext_vector_type(4))) float f32x4;

constexpr int K = 256;
constexpr int D = 64;

constexpr int BLK_A = 512;      // 8 waves
constexpr int GRID_A = 1024;    // 2 blocks/CU (LDS 2x65KB = 130KB <= 160KB)
constexpr int WPB_A = BLK_A / 64;

constexpr int BLK_B = 1024;
constexpr int GRID_B = 512;     // 2 blocks/CU

struct alignas(16) PackW { unsigned int w[4]; };

// fire-and-forget LDS f32 atomic add (low 32 bits of generic ptr = LDS offset)
#define DS_ADD_F32(addr32, val) \
  asm volatile("ds_add_f32 %0, %1" :: "v"(addr32), "v"(val))

__device__ __forceinline__ unsigned int pack_hi(unsigned int a, unsigned int b) {
  return (a >> 16) | (b & 0xffff0000u);
}

__device__ __forceinline__ void split8(const float4 a, const float4 b,
                                       bf16x8& s0, bf16x8& s1) {
  PackW p0, p1;
  const float fa[8] = {a.x, a.y, a.z, a.w, b.x, b.y, b.z, b.w};
#pragma unroll
  for (int i = 0; i < 4; ++i) {
    float f0 = fa[2 * i], f1 = fa[2 * i + 1];
    unsigned u0 = __float_as_uint(f0), u1 = __float_as_uint(f1);
    p0.w[i] = pack_hi(u0, u1);
    float r0 = f0 - __uint_as_float(u0 & 0xffff0000u);
    float r1 = f1 - __uint_as_float(u1 & 0xffff0000u);
    p1.w[i] = pack_hi(__float_as_uint(r0), __float_as_uint(r1));
  }
  s0 = __builtin_bit_cast(bf16x8, p0);
  s1 = __builtin_bit_cast(bf16x8, p1);
}

// ---------------- A: assign (labels + loss only) ----------------
__global__ __launch_bounds__(BLK_A, 2) void assign_kernel(
    const float* __restrict__ emb,
    const float* __restrict__ centers,
    float* __restrict__ out_labels,
    float* __restrict__ ws_loss,
    int N)
{
  __shared__ __align__(16) unsigned short Bls[2 * K * D];   // 64 KB
  __shared__ float hneg_lds[K];
  __shared__ float red[WPB_A];

  const int tid = threadIdx.x;

  for (int e = tid; e < K * D; e += BLK_A) {
    int j = e >> 6, d = e & 63;
    float cv = centers[e];
    unsigned u = __float_as_uint(cv);
    unsigned short h0 = (unsigned short)(u >> 16);
    float r = cv - __uint_as_float(u & 0xffff0000u);
    unsigned short h1 = (unsigned short)(__float_as_uint(r) >> 16);
    int nt = j >> 4, c = j & 15;
    int si = nt * 1024 + c * 64 + (d ^ ((c & 7) << 3));
    Bls[si] = h0;
    Bls[16384 + si] = h1;
  }
  if (tid < K) {
    const float4* cp = (const float4*)(centers + tid * D);
    float s = 0.f;
#pragma unroll
    for (int q = 0; q < 16; ++q) {
      float4 v = cp[q];
      s = fmaf(v.x, v.x, s); s = fmaf(v.y, v.y, s);
      s = fmaf(v.z, v.z, s); s = fmaf(v.w, v.w, s);
    }
    hneg_lds[tid] = -0.5f * s;
  }
  __syncthreads();

  const int lane = tid & 63;
  const int wid  = tid >> 6;
  const int g    = lane >> 4;
  const int cc   = lane & 15;
  const int swzm = (cc & 7) << 3;
  const int bRow = cc * 64;
  const int bk0 = (8 * g) ^ swzm;
  const int bk1 = (32 + 8 * g) ^ swzm;

  float hreg[16];
#pragma unroll
  for (int nt = 0; nt < 16; ++nt) hreg[nt] = hneg_lds[nt * 16 + cc];

  float lossS = 0.f, lossX = 0.f;
  const int TILES = N >> 5;

  for (int tile = blockIdx.x * WPB_A + wid; tile < TILES; tile += GRID_A * WPB_A) {
    const int base = tile << 5;

    float4 xa[2][2][2];
    bf16x8 fx[2][2][2];
#pragma unroll
    for (int Mt = 0; Mt < 2; ++Mt) {
#pragma unroll
      for (int ks = 0; ks < 2; ++ks) {
        const float4* rp = (const float4*)(emb + (size_t)(base + Mt * 16 + cc) * D + ks * 32 + g * 8);
        xa[Mt][ks][0] = rp[0];
        xa[Mt][ks][1] = rp[1];
      }
#pragma unroll
      for (int ks = 0; ks < 2; ++ks)
        split8(xa[Mt][ks][0], xa[Mt][ks][1], fx[Mt][ks][0], fx[Mt][ks][1]);
#pragma unroll
      for (int ks = 0; ks < 2; ++ks)
#pragma unroll
        for (int h = 0; h < 2; ++h) {
          float4 v = xa[Mt][ks][h];
          lossX = fmaf(v.x, v.x, lossX); lossX = fmaf(v.y, v.y, lossX);
          lossX = fmaf(v.z, v.z, lossX); lossX = fmaf(v.w, v.w, lossX);
        }
    }

    float bE[2][4];
#pragma unroll
    for (int Mt = 0; Mt < 2; ++Mt)
#pragma unroll
      for (int r = 0; r < 4; ++r) bE[Mt][r] = -3.0e38f;

#pragma unroll
    for (int nt = 0; nt < 16; ++nt) {
      float h = hreg[nt];
      f32x4 ci = {h, h, h, h};
      bf16x8 b00 = *(const bf16x8*)&Bls[nt * 1024 + bRow + bk0];
      bf16x8 b01 = *(const bf16x8*)&Bls[16384 + nt * 1024 + bRow + bk0];
      bf16x8 b10 = *(const bf16x8*)&Bls[nt * 1024 + bRow + bk1];
      bf16x8 b11 = *(const bf16x8*)&Bls[16384 + nt * 1024 + bRow + bk1];
      f32x4 a0, a1;
      a0 = __builtin_amdgcn_mfma_f32_16x16x32_bf16(fx[0][0][0], b00, ci, 0, 0, 0);
      a0 = __builtin_amdgcn_mfma_f32_16x16x32_bf16(fx[0][0][1], b00, a0, 0, 0, 0);
      a0 = __builtin_amdgcn_mfma_f32_16x16x32_bf16(fx[0][0][0], b01, a0, 0, 0, 0);
      a0 = __builtin_amdgcn_mfma_f32_16x16x32_bf16(fx[0][1][0], b10, a0, 0, 0, 0);
      a0 = __builtin_amdgcn_mfma_f32_16x16x32_bf16(fx[0][1][1], b10, a0, 0, 0, 0);
      a0 = __builtin_amdgcn_mfma_f32_16x16x32_bf16(fx[0][1][0], b11, a0, 0, 0, 0);
      a1 = __builtin_amdgcn_mfma_f32_16x16x32_bf16(fx[1][0][0], b00, ci, 0, 0, 0);
      a1 = __builtin_amdgcn_mfma_f32_16x16x32_bf16(fx[1][0][1], b00, a1, 0, 0, 0);
      a1 = __builtin_amdgcn_mfma_f32_16x16x32_bf16(fx[1][0][0], b01, a1, 0, 0, 0);
      a1 = __builtin_amdgcn_mfma_f32_16x16x32_bf16(fx[1][1][0], b10, a1, 0, 0, 0);
      a1 = __builtin_amdgcn_mfma_f32_16x16x32_bf16(fx[1][1][1], b10, a1, 0, 0, 0);
      a1 = __builtin_amdgcn_mfma_f32_16x16x32_bf16(fx[1][1][0], b11, a1, 0, 0, 0);

      unsigned ib = (unsigned)(nt << 4) | (unsigned)cc;
#pragma unroll
      for (int r = 0; r < 4; ++r) {
        bE[0][r] = fmaxf(bE[0][r], __uint_as_float((__float_as_uint(a0[r]) & 0xFFFFFF00u) | ib));
        bE[1][r] = fmaxf(bE[1][r], __uint_as_float((__float_as_uint(a1[r]) & 0xFFFFFF00u) | ib));
      }
    }

#pragma unroll
    for (int Mt = 0; Mt < 2; ++Mt)
#pragma unroll
      for (int r = 0; r < 4; ++r)
#pragma unroll
        for (int m = 1; m <= 8; m <<= 1)
          bE[Mt][r] = fmaxf(bE[Mt][r], __shfl_xor(bE[Mt][r], m));

#pragma unroll
    for (int Mt = 0; Mt < 2; ++Mt) {
      float v01 = (cc & 1) ? bE[Mt][1] : bE[Mt][0];
      float v23 = (cc & 1) ? bE[Mt][3] : bE[Mt][2];
      float vv  = (cc & 2) ? v23 : v01;
      if (cc < 4) {
        int vi = (int)(__float_as_uint(vv) & 255u);
        out_labels[base + Mt * 16 + g * 4 + cc] = (float)vi;
        lossS += vv;
      }
    }
  }

  float acc = fmaf(-2.f, lossS, lossX);
#pragma unroll
  for (int off = 32; off > 0; off >>= 1) acc += __shfl_down(acc, off);
  if (lane == 0) red[wid] = acc;
  __syncthreads();
  if (tid == 0) {
    float t = 0.f;
#pragma unroll
    for (int w = 0; w < WPB_A; ++w) t += red[w];
    unsafeAtomicAdd(ws_loss, t);
  }
}

// ---------------- B: streaming segment sum ----------------
__global__ __launch_bounds__(BLK_B, 2) void segsum_kernel(
    const float* __restrict__ emb,
    const float* __restrict__ labels_f,
    float* __restrict__ ws_seg,
    int*   __restrict__ ws_cnt,
    int N)
{
  __shared__ float seg_lds[K * D];   // [k][d^(k&31)]  64 KB
  __shared__ int   cnt_lds[K];

  const int tid = threadIdx.x;
  for (int e = tid; e < K * D; e += BLK_B) seg_lds[e] = 0.f;
  if (tid < K) cnt_lds[tid] = 0;
  __syncthreads();

  const unsigned segbase = (unsigned)(size_t)seg_lds;
  const int q = tid & 3;                    // 4 lanes per sample
  const int SPP = GRID_B * BLK_B / 4;       // samples per pass (131072)

  for (int s = (blockIdx.x * BLK_B + tid) >> 2; s < N; s += SPP) {
    int lbl = (int)labels_f[s];
    const float4* rp = (const float4*)(emb + (size_t)s * D + q * 16);
    float4 v0 = rp[0], v1 = rp[1], v2 = rp[2], v3 = rp[3];
    unsigned sb = segbase + ((unsigned)lbl << 8);
    int sw = lbl & 31;
    int d0 = q * 16;
    DS_ADD_F32(sb + (unsigned)(((d0 +  0) ^ sw) << 2), v0.x);
    DS_ADD_F32(sb + (unsigned)(((d0 +  1) ^ sw) << 2), v0.y);
    DS_ADD_F32(sb + (unsigned)(((d0 +  2) ^ sw) << 2), v0.z);
    DS_ADD_F32(sb + (unsigned)(((d0 +  3) ^ sw) << 2), v0.w);
    DS_ADD_F32(sb + (unsigned)(((d0 +  4) ^ sw) << 2), v1.x);
    DS_ADD_F32(sb + (unsigned)(((d0 +  5) ^ sw) << 2), v1.y);
    DS_ADD_F32(sb + (unsigned)(((d0 +  6) ^ sw) << 2), v1.z);
    DS_ADD_F32(sb + (unsigned)(((d0 +  7) ^ sw) << 2), v1.w);
    DS_ADD_F32(sb + (unsigned)(((d0 +  8) ^ sw) << 2), v2.x);
    DS_ADD_F32(sb + (unsigned)(((d0 +  9) ^ sw) << 2), v2.y);
    DS_ADD_F32(sb + (unsigned)(((d0 + 10) ^ sw) << 2), v2.z);
    DS_ADD_F32(sb + (unsigned)(((d0 + 11) ^ sw) << 2), v2.w);
    DS_ADD_F32(sb + (unsigned)(((d0 + 12) ^ sw) << 2), v3.x);
    DS_ADD_F32(sb + (unsigned)(((d0 + 13) ^ sw) << 2), v3.y);
    DS_ADD_F32(sb + (unsigned)(((d0 + 14) ^ sw) << 2), v3.z);
    DS_ADD_F32(sb + (unsigned)(((d0 + 15) ^ sw) << 2), v3.w);
    if (q == 0) atomicAdd(&cnt_lds[lbl], 1);
  }

  asm volatile("s_waitcnt lgkmcnt(0)" ::: "memory");
  __syncthreads();

  for (int e = tid; e < K * D; e += BLK_B) {
    int k = e >> 6, d = e & 63;
    unsafeAtomicAdd(&ws_seg[e], seg_lds[(k << 6) + (d ^ (k & 31))]);
  }
  if (tid < K) atomicAdd(&ws_cnt[tid], cnt_lds[tid]);
}

// ---------------- C: finalize ----------------
__global__ void finalize_kernel(
    const float* __restrict__ centers,
    const int* __restrict__ counts,
    const float* __restrict__ ws_seg,
    const int* __restrict__ ws_cnt,
    const float* __restrict__ ws_loss,
    float* __restrict__ out_loss,
    float* __restrict__ out_centers,
    float* __restrict__ out_counts,
    int N)
{
  int idx = blockIdx.x * blockDim.x + threadIdx.x;
  if (idx < K * D) {
    int k = idx >> 6;
    float oldw = (float)counts[k];
    float neww = (float)(counts[k] + ws_cnt[k]);
    out_centers[idx] = fmaf(oldw, centers[idx], ws_seg[idx]) / neww;
  }
  if (idx < K) out_counts[idx] = (float)(counts[idx] + ws_cnt[idx]);
  if (idx == 0) out_loss[0] = ws_loss[0] / (float)N;
}

extern "C" void kernel_launch(void* const* d_in, const int* in_sizes, int n_in,
                              void* d_out, int out_size, void* d_ws, size_t ws_size,
                              hipStream_t stream) {
  const float* emb     = (const float*)d_in[0];
  const float* centers = (const float*)d_in[1];
  const int*   counts  = (const int*)d_in[2];

  const int Kn = in_sizes[2];        // 256
  const int Dn = in_sizes[1] / Kn;   // 64
  const int N  = in_sizes[0] / Dn;   // 500000

  float* out         = (float*)d_out;
  float* out_labels  = out;
  float* out_loss    = out + N;
  float* out_centers = out + N + 1;
  float* out_counts  = out + N + 1 + (size_t)Kn * Dn;

  float* ws_seg  = (float*)d_ws;
  int*   ws_cnt  = (int*)(ws_seg + (size_t)Kn * Dn);
  float* ws_loss = (float*)(ws_cnt + Kn);

  hipMemsetAsync(d_ws, 0, (size_t)(Kn * Dn + Kn + 1) * sizeof(float), stream);

  hipLaunchKernelGGL(assign_kernel, dim3(GRID_A), dim3(BLK_A), 0, stream,
                     emb, centers, out_labels, ws_loss, N);

  hipLaunchKernelGGL(segsum_kernel, dim3(GRID_B), dim3(BLK_B), 0, stream,
                     emb, out_labels, ws_seg, ws_cnt, N);

  hipLaunchKernelGGL(finalize_kernel, dim3((Kn * Dn + 255) / 256), dim3(256), 0, stream,
                     centers, counts, ws_seg, ws_cnt, ws_loss,
                     out_loss, out_centers, out_counts, N);
}

// Round 8
// 440.032 us; speedup vs baseline: 2.2560x; 1.3687x over previous
//
#include <hip/hip_runtime.h>

// DCN module on MI355X — fissioned design:
//   A) assign_kernel: bf16-split MFMA argmin -> labels + loss
//   B) segsum_kernel: streaming re-read of emb + labels -> LDS ds_add seg-sum
//   C) finalize_kernel: centers/counts/loss epilogue
//
// Measured __launch_bounds__ ladder (2nd arg -> arch VGPR): 8->32, 4->64,
// 2->128, (768,3)->84. With MFMA present the unified VGPR/AGPR file appears
// split ~50/50, so the usable arch cap is (512/arg)/2. Full unroll of the
// 16-iter nt-loop let the scheduler hoist up to 64 ds_read b-fragments ->
// live-range blowup -> spills at any cap. Fix: unroll 4.
//
// Output (float32 flat): [0,N) labels | [N] loss | centers [K][D] | counts [K]

typedef __attribute__((ext_vector_type(8))) short bf16x8;
typedef __attribute__((ext_vector_type(4))) float f32x4;

constexpr int K = 256;
constexpr int D = 64;

constexpr int BLK_A = 512;      // 8 waves
constexpr int GRID_A = 1024;    // 2 blocks/CU (LDS 2x65KB = 130KB <= 160KB)
constexpr int WPB_A = BLK_A / 64;

constexpr int BLK_B = 1024;
constexpr int GRID_B = 512;     // 2 blocks/CU

struct alignas(16) PackW { unsigned int w[4]; };

// fire-and-forget LDS f32 atomic add (low 32 bits of generic ptr = LDS offset)
#define DS_ADD_F32(addr32, val) \
  asm volatile("ds_add_f32 %0, %1" :: "v"(addr32), "v"(val))

__device__ __forceinline__ unsigned int pack_hi(unsigned int a, unsigned int b) {
  return (a >> 16) | (b & 0xffff0000u);
}

__device__ __forceinline__ void split8(const float4 a, const float4 b,
                                       bf16x8& s0, bf16x8& s1) {
  PackW p0, p1;
  const float fa[8] = {a.x, a.y, a.z, a.w, b.x, b.y, b.z, b.w};
#pragma unroll
  for (int i = 0; i < 4; ++i) {
    float f0 = fa[2 * i], f1 = fa[2 * i + 1];
    unsigned u0 = __float_as_uint(f0), u1 = __float_as_uint(f1);
    p0.w[i] = pack_hi(u0, u1);
    float r0 = f0 - __uint_as_float(u0 & 0xffff0000u);
    float r1 = f1 - __uint_as_float(u1 & 0xffff0000u);
    p1.w[i] = pack_hi(__float_as_uint(r0), __float_as_uint(r1));
  }
  s0 = __builtin_bit_cast(bf16x8, p0);
  s1 = __builtin_bit_cast(bf16x8, p1);
}

// ---------------- A: assign (labels + loss only) ----------------
__global__ __launch_bounds__(BLK_A, 2) void assign_kernel(
    const float* __restrict__ emb,
    const float* __restrict__ centers,
    float* __restrict__ out_labels,
    float* __restrict__ ws_loss,
    int N)
{
  __shared__ __align__(16) unsigned short Bls[2 * K * D];   // 64 KB
  __shared__ float hneg_lds[K];
  __shared__ float red[WPB_A];

  const int tid = threadIdx.x;

  for (int e = tid; e < K * D; e += BLK_A) {
    int j = e >> 6, d = e & 63;
    float cv = centers[e];
    unsigned u = __float_as_uint(cv);
    unsigned short h0 = (unsigned short)(u >> 16);
    float r = cv - __uint_as_float(u & 0xffff0000u);
    unsigned short h1 = (unsigned short)(__float_as_uint(r) >> 16);
    int nt = j >> 4, c = j & 15;
    int si = nt * 1024 + c * 64 + (d ^ ((c & 7) << 3));
    Bls[si] = h0;
    Bls[16384 + si] = h1;
  }
  if (tid < K) {
    const float4* cp = (const float4*)(centers + tid * D);
    float s = 0.f;
#pragma unroll
    for (int q = 0; q < 16; ++q) {
      float4 v = cp[q];
      s = fmaf(v.x, v.x, s); s = fmaf(v.y, v.y, s);
      s = fmaf(v.z, v.z, s); s = fmaf(v.w, v.w, s);
    }
    hneg_lds[tid] = -0.5f * s;
  }
  __syncthreads();

  const int lane = tid & 63;
  const int wid  = tid >> 6;
  const int g    = lane >> 4;
  const int cc   = lane & 15;
  const int swzm = (cc & 7) << 3;
  const int bRow = cc * 64;
  const int bk0 = (8 * g) ^ swzm;
  const int bk1 = (32 + 8 * g) ^ swzm;

  float hreg[16];
#pragma unroll
  for (int nt = 0; nt < 16; ++nt) hreg[nt] = hneg_lds[nt * 16 + cc];

  float lossS = 0.f, lossX = 0.f;
  const int TILES = N >> 5;

  for (int tile = blockIdx.x * WPB_A + wid; tile < TILES; tile += GRID_A * WPB_A) {
    const int base = tile << 5;

    float4 xa[2][2][2];
    bf16x8 fx[2][2][2];
#pragma unroll
    for (int Mt = 0; Mt < 2; ++Mt) {
#pragma unroll
      for (int ks = 0; ks < 2; ++ks) {
        const float4* rp = (const float4*)(emb + (size_t)(base + Mt * 16 + cc) * D + ks * 32 + g * 8);
        xa[Mt][ks][0] = rp[0];
        xa[Mt][ks][1] = rp[1];
      }
#pragma unroll
      for (int ks = 0; ks < 2; ++ks)
        split8(xa[Mt][ks][0], xa[Mt][ks][1], fx[Mt][ks][0], fx[Mt][ks][1]);
#pragma unroll
      for (int ks = 0; ks < 2; ++ks)
#pragma unroll
        for (int h = 0; h < 2; ++h) {
          float4 v = xa[Mt][ks][h];
          lossX = fmaf(v.x, v.x, lossX); lossX = fmaf(v.y, v.y, lossX);
          lossX = fmaf(v.z, v.z, lossX); lossX = fmaf(v.w, v.w, lossX);
        }
    }

    float bE[2][4];
#pragma unroll
    for (int Mt = 0; Mt < 2; ++Mt)
#pragma unroll
      for (int r = 0; r < 4; ++r) bE[Mt][r] = -3.0e38f;

    // unroll 4 (not 16): bounds ds_read hoisting -> keeps arch-VGPR need <128
#pragma unroll 4
    for (int nt = 0; nt < 16; ++nt) {
      float h = hreg[nt];
      f32x4 ci = {h, h, h, h};
      bf16x8 b00 = *(const bf16x8*)&Bls[nt * 1024 + bRow + bk0];
      bf16x8 b01 = *(const bf16x8*)&Bls[16384 + nt * 1024 + bRow + bk0];
      bf16x8 b10 = *(const bf16x8*)&Bls[nt * 1024 + bRow + bk1];
      bf16x8 b11 = *(const bf16x8*)&Bls[16384 + nt * 1024 + bRow + bk1];
      f32x4 a0, a1;
      a0 = __builtin_amdgcn_mfma_f32_16x16x32_bf16(fx[0][0][0], b00, ci, 0, 0, 0);
      a0 = __builtin_amdgcn_mfma_f32_16x16x32_bf16(fx[0][0][1], b00, a0, 0, 0, 0);
      a0 = __builtin_amdgcn_mfma_f32_16x16x32_bf16(fx[0][0][0], b01, a0, 0, 0, 0);
      a0 = __builtin_amdgcn_mfma_f32_16x16x32_bf16(fx[0][1][0], b10, a0, 0, 0, 0);
      a0 = __builtin_amdgcn_mfma_f32_16x16x32_bf16(fx[0][1][1], b10, a0, 0, 0, 0);
      a0 = __builtin_amdgcn_mfma_f32_16x16x32_bf16(fx[0][1][0], b11, a0, 0, 0, 0);
      a1 = __builtin_amdgcn_mfma_f32_16x16x32_bf16(fx[1][0][0], b00, ci, 0, 0, 0);
      a1 = __builtin_amdgcn_mfma_f32_16x16x32_bf16(fx[1][0][1], b00, a1, 0, 0, 0);
      a1 = __builtin_amdgcn_mfma_f32_16x16x32_bf16(fx[1][0][0], b01, a1, 0, 0, 0);
      a1 = __builtin_amdgcn_mfma_f32_16x16x32_bf16(fx[1][1][0], b10, a1, 0, 0, 0);
      a1 = __builtin_amdgcn_mfma_f32_16x16x32_bf16(fx[1][1][1], b10, a1, 0, 0, 0);
      a1 = __builtin_amdgcn_mfma_f32_16x16x32_bf16(fx[1][1][0], b11, a1, 0, 0, 0);

      unsigned ib = (unsigned)(nt << 4) | (unsigned)cc;
#pragma unroll
      for (int r = 0; r < 4; ++r) {
        bE[0][r] = fmaxf(bE[0][r], __uint_as_float((__float_as_uint(a0[r]) & 0xFFFFFF00u) | ib));
        bE[1][r] = fmaxf(bE[1][r], __uint_as_float((__float_as_uint(a1[r]) & 0xFFFFFF00u) | ib));
      }
    }

#pragma unroll
    for (int Mt = 0; Mt < 2; ++Mt)
#pragma unroll
      for (int r = 0; r < 4; ++r)
#pragma unroll
        for (int m = 1; m <= 8; m <<= 1)
          bE[Mt][r] = fmaxf(bE[Mt][r], __shfl_xor(bE[Mt][r], m));

#pragma unroll
    for (int Mt = 0; Mt < 2; ++Mt) {
      float v01 = (cc & 1) ? bE[Mt][1] : bE[Mt][0];
      float v23 = (cc & 1) ? bE[Mt][3] : bE[Mt][2];
      float vv  = (cc & 2) ? v23 : v01;
      if (cc < 4) {
        int vi = (int)(__float_as_uint(vv) & 255u);
        out_labels[base + Mt * 16 + g * 4 + cc] = (float)vi;
        lossS += vv;
      }
    }
  }

  float acc = fmaf(-2.f, lossS, lossX);
#pragma unroll
  for (int off = 32; off > 0; off >>= 1) acc += __shfl_down(acc, off);
  if (lane == 0) red[wid] = acc;
  __syncthreads();
  if (tid == 0) {
    float t = 0.f;
#pragma unroll
    for (int w = 0; w < WPB_A; ++w) t += red[w];
    unsafeAtomicAdd(ws_loss, t);
  }
}

// ---------------- B: streaming segment sum ----------------
__global__ __launch_bounds__(BLK_B, 2) void segsum_kernel(
    const float* __restrict__ emb,
    const float* __restrict__ labels_f,
    float* __restrict__ ws_seg,
    int*   __restrict__ ws_cnt,
    int N)
{
  __shared__ float seg_lds[K * D];   // [k][d^(k&31)]  64 KB
  __shared__ int   cnt_lds[K];

  const int tid = threadIdx.x;
  for (int e = tid; e < K * D; e += BLK_B) seg_lds[e] = 0.f;
  if (tid < K) cnt_lds[tid] = 0;
  __syncthreads();

  const unsigned segbase = (unsigned)(size_t)seg_lds;
  const int q = tid & 3;                    // 4 lanes per sample
  const int SPP = GRID_B * BLK_B / 4;       // samples per pass (131072)

  for (int s = (blockIdx.x * BLK_B + tid) >> 2; s < N; s += SPP) {
    int lbl = (int)labels_f[s];
    const float4* rp = (const float4*)(emb + (size_t)s * D + q * 16);
    float4 v0 = rp[0], v1 = rp[1], v2 = rp[2], v3 = rp[3];
    unsigned sb = segbase + ((unsigned)lbl << 8);
    int sw = lbl & 31;
    int d0 = q * 16;
    DS_ADD_F32(sb + (unsigned)(((d0 +  0) ^ sw) << 2), v0.x);
    DS_ADD_F32(sb + (unsigned)(((d0 +  1) ^ sw) << 2), v0.y);
    DS_ADD_F32(sb + (unsigned)(((d0 +  2) ^ sw) << 2), v0.z);
    DS_ADD_F32(sb + (unsigned)(((d0 +  3) ^ sw) << 2), v0.w);
    DS_ADD_F32(sb + (unsigned)(((d0 +  4) ^ sw) << 2), v1.x);
    DS_ADD_F32(sb + (unsigned)(((d0 +  5) ^ sw) << 2), v1.y);
    DS_ADD_F32(sb + (unsigned)(((d0 +  6) ^ sw) << 2), v1.z);
    DS_ADD_F32(sb + (unsigned)(((d0 +  7) ^ sw) << 2), v1.w);
    DS_ADD_F32(sb + (unsigned)(((d0 +  8) ^ sw) << 2), v2.x);
    DS_ADD_F32(sb + (unsigned)(((d0 +  9) ^ sw) << 2), v2.y);
    DS_ADD_F32(sb + (unsigned)(((d0 + 10) ^ sw) << 2), v2.z);
    DS_ADD_F32(sb + (unsigned)(((d0 + 11) ^ sw) << 2), v2.w);
    DS_ADD_F32(sb + (unsigned)(((d0 + 12) ^ sw) << 2), v3.x);
    DS_ADD_F32(sb + (unsigned)(((d0 + 13) ^ sw) << 2), v3.y);
    DS_ADD_F32(sb + (unsigned)(((d0 + 14) ^ sw) << 2), v3.z);
    DS_ADD_F32(sb + (unsigned)(((d0 + 15) ^ sw) << 2), v3.w);
    if (q == 0) atomicAdd(&cnt_lds[lbl], 1);
  }

  asm volatile("s_waitcnt lgkmcnt(0)" ::: "memory");
  __syncthreads();

  for (int e = tid; e < K * D; e += BLK_B) {
    int k = e >> 6, d = e & 63;
    unsafeAtomicAdd(&ws_seg[e], seg_lds[(k << 6) + (d ^ (k & 31))]);
  }
  if (tid < K) atomicAdd(&ws_cnt[tid], cnt_lds[tid]);
}

// ---------------- C: finalize ----------------
__global__ void finalize_kernel(
    const float* __restrict__ centers,
    const int* __restrict__ counts,
    const float* __restrict__ ws_seg,
    const int* __restrict__ ws_cnt,
    const float* __restrict__ ws_loss,
    float* __restrict__ out_loss,
    float* __restrict__ out_centers,
    float* __restrict__ out_counts,
    int N)
{
  int idx = blockIdx.x * blockDim.x + threadIdx.x;
  if (idx < K * D) {
    int k = idx >> 6;
    float oldw = (float)counts[k];
    float neww = (float)(counts[k] + ws_cnt[k]);
    out_centers[idx] = fmaf(oldw, centers[idx], ws_seg[idx]) / neww;
  }
  if (idx < K) out_counts[idx] = (float)(counts[idx] + ws_cnt[idx]);
  if (idx == 0) out_loss[0] = ws_loss[0] / (float)N;
}

extern "C" void kernel_launch(void* const* d_in, const int* in_sizes, int n_in,
                              void* d_out, int out_size, void* d_ws, size_t ws_size,
                              hipStream_t stream) {
  const float* emb     = (const float*)d_in[0];
  const float* centers = (const float*)d_in[1];
  const int*   counts  = (const int*)d_in[2];

  const int Kn = in_sizes[2];        // 256
  const int Dn = in_sizes[1] / Kn;   // 64
  const int N  = in_sizes[0] / Dn;   // 500000

  float* out         = (float*)d_out;
  float* out_labels  = out;
  float* out_loss    = out + N;
  float* out_centers = out + N + 1;
  float* out_counts  = out + N + 1 + (size_t)Kn * Dn;

  float* ws_seg  = (float*)d_ws;
  int*   ws_cnt  = (int*)(ws_seg + (size_t)Kn * Dn);
  float* ws_loss = (float*)(ws_cnt + Kn);

  hipMemsetAsync(d_ws, 0, (size_t)(Kn * Dn + Kn + 1) * sizeof(float), stream);

  hipLaunchKernelGGL(assign_kernel, dim3(GRID_A), dim3(BLK_A), 0, stream,
                     emb, centers, out_labels, ws_loss, N);

  hipLaunchKernelGGL(segsum_kernel, dim3(GRID_B), dim3(BLK_B), 0, stream,
                     emb, out_labels, ws_seg, ws_cnt, N);

  hipLaunchKernelGGL(finalize_kernel, dim3((Kn * Dn + 255) / 256), dim3(256), 0, stream,
                     centers, counts, ws_seg, ws_cnt, ws_loss,
                     out_loss, out_centers, out_counts, N);
}